// Round 7
// baseline (645.586 us; speedup 1.0000x reference)
//
#include <hip/hip_runtime.h>

#define HH 512
#define WW 512
#define PD 544                          // 512 + 2*16
#define PADN (3 * PD * PD)              // 887808 bf16 elements
#define OUTN (3 * HH * WW)
#define NB 128
#define KSTR 16384                      // 128*128 floats between taps

// ---------------- pad + out-zero: fp32 img -> bf16 edge-padded ----------------
__global__ __launch_bounds__(256) void pad_kernel(const float* __restrict__ img,
                                                  unsigned short* __restrict__ gpad,
                                                  float* __restrict__ out) {
    int idx = blockIdx.x * 256 + threadIdx.x;
    if (idx < OUTN) out[idx] = 0.0f;           // zero the atomic target
    if (idx >= PADN) return;
    int c  = idx / (PD * PD);
    int r  = idx - c * (PD * PD);
    int py = r / PD;
    int px = r - py * PD;
    int iy = min(max(py - 16, 0), HH - 1);
    int ix = min(max(px - 16, 0), WW - 1);
    union { float f; unsigned u; } v;
    v.f = img[(c * HH + iy) * WW + ix];
    unsigned u = v.u + 0x7FFFu + ((v.u >> 16) & 1u);   // RNE bf16
    gpad[idx] = (unsigned short)(u >> 16);
}

// ---- async global->LDS (wave-uniform LDS base; HW puts lane i at base+i*size) ----
__device__ __forceinline__ void async16u(const unsigned short* g, unsigned short* l) {
    __builtin_amdgcn_global_load_lds((const __attribute__((address_space(1))) void*)g,
                                     (__attribute__((address_space(3))) void*)l, 16, 0, 0);
}
__device__ __forceinline__ float bflo(unsigned d) { union { unsigned u; float f; } x; x.u = d << 16;         return x.f; }
__device__ __forceinline__ float bfhi(unsigned d) { union { unsigned u; float f; } x; x.u = d & 0xFFFF0000u; return x.f; }

// ---------------- main kernel ----------------
// Grid = 4 u-chunks x 128 h x 2 wt = 1024 blocks (4/CU, 16 waves/CU, 4/SIMD)
// of 256 thr (4 waves, wave = dy). Lane owns (wb, dy, 3c, 4oj) = 12 accs.
// WEIGHTS: global->register direct (L2/L3-resident), double-buffered wA/wB one
// iteration ahead; textual-macro unroll-2 (no dynamic reg indexing -> no
// scratch; rounds 2/5 lesson). IMAGE: bf16 rows, 8-slot LDS ring via
// global_load_lds; window = 9 ds_read_b64/channel (8B/lane, ~conflict-free).
// Sync per iter: own-stage s_waitcnt vmcnt(0) + one s_barrier; 4 waves/SIMD
// (round-7 change, was 2) hide the drain+barrier+LDS-latency critical path.
// u-chunks combine via atomicAdd into the pad_kernel-zeroed output.
// LDS 13.8 KB; __launch_bounds__(256,4) -> 128-VGPR cap (R6 measured 124).
__global__ __launch_bounds__(256, 4) void reblur_kernel(const unsigned short* __restrict__ gpad,
                                                        const float* __restrict__ Kern,
                                                        float* __restrict__ out) {
    __shared__ unsigned short s_img[8][3][288];   // 13824 B, ring over padded row

    const int lane = threadIdx.x & 63;
    const int dy   = threadIdx.x >> 6;            // wave id 0..3
    const int uq   = blockIdx.x >> 8;             // u-chunk 0..3
    const int bb   = blockIdx.x & 255;
    const int h    = bb >> 1;                     // 0..127
    const int wt   = bb & 1;                      // 0..1
    const int ua   = (uq == 0) ? 0 : (1 + 8 * uq);   // 0,9,17,25
    const int n    = (uq == 0) ? 9 : 8;              // covers u: 0-8,9-16,17-24,25-32
    const int kofs = h * NB + wt * 64 + lane;     // per-lane weight dword offset

    // ---- prologue: wave dy stages image row 4h+ua+dy (x3 channels); all waves
    //      load weight row u=ua into wA ----
    if (lane < 36) {
        const int r = 4 * h + ua + dy;
#pragma unroll
        for (int c = 0; c < 3; ++c)
            async16u(gpad + ((size_t)(c * PD + r) * PD + 256 * wt) + 8 * lane,
                     &s_img[r & 7][c][0]);
    }
    float wA[33], wB[33];
#pragma unroll
    for (int v = 0; v < 33; ++v)
        wA[v] = Kern[(size_t)(ua * 33 + v) * KSTR + kofs];

    float acc[3][4];
#pragma unroll
    for (int c = 0; c < 3; ++c)
#pragma unroll
        for (int oj = 0; oj < 4; ++oj) acc[c][oj] = 0.0f;

// One pipelined iteration. WCUR: weights for u=ua+tt (in regs); WNXT: buffer
// to receive u=ua+tt+1. All array indices compile-time constants.
#define R7_ITER(WCUR, WNXT, TT)                                                  \
    {                                                                            \
        const int tt = (TT);                                                     \
        asm volatile("s_waitcnt vmcnt(0)" ::: "memory");                         \
        __builtin_amdgcn_s_barrier();                                            \
        if (tt + 1 < n) {                                                        \
            const int un = ua + tt + 1;                                          \
            _Pragma("unroll")                                                    \
            for (int v = 0; v < 33; ++v)                                         \
                WNXT[v] = Kern[(size_t)(un * 33 + v) * KSTR + kofs];             \
            if (dy == (tt & 3) && lane < 36) {                                   \
                const int r = 4 * h + ua + tt + 4;                               \
                _Pragma("unroll")                                                \
                for (int c = 0; c < 3; ++c)                                      \
                    async16u(gpad + ((size_t)(c * PD + r) * PD + 256 * wt) + 8 * lane, \
                             &s_img[r & 7][c][0]);                               \
            }                                                                    \
        }                                                                        \
        const int slot = (4 * h + ua + tt + dy) & 7;                             \
        _Pragma("unroll")                                                        \
        for (int c = 0; c < 3; ++c) {                                            \
            float wf[36];                                                        \
            const unsigned short* sp = &s_img[slot][c][4 * lane];                \
            _Pragma("unroll")                                                    \
            for (int j = 0; j < 9; ++j) {                                        \
                const uint2 dd = *(const uint2*)(sp + 4 * j);                    \
                wf[4 * j + 0] = bflo(dd.x);                                      \
                wf[4 * j + 1] = bfhi(dd.x);                                      \
                wf[4 * j + 2] = bflo(dd.y);                                      \
                wf[4 * j + 3] = bfhi(dd.y);                                      \
            }                                                                    \
            _Pragma("unroll")                                                    \
            for (int v = 0; v < 33; ++v) {                                       \
                _Pragma("unroll")                                                \
                for (int oj = 0; oj < 4; ++oj)                                   \
                    acc[c][oj] = fmaf(wf[v + oj], WCUR[v], acc[c][oj]);          \
            }                                                                    \
        }                                                                        \
    }

    int t = 0;
#pragma unroll 1
    for (; t + 1 < n; t += 2) {
        R7_ITER(wA, wB, t);
        R7_ITER(wB, wA, t + 1);
    }
    if (t < n) {           // n odd (chunk 0): tail iter computes with wA
        R7_ITER(wA, wB, t);
    }
#undef R7_ITER

    // ---- epilogue: 4 u-chunks accumulate into the pad_kernel-zeroed output ----
    const int xb = 4 * (wt * 64 + lane);
#pragma unroll
    for (int c = 0; c < 3; ++c) {
        float* op = out + (size_t)(c * HH + 4 * h + dy) * WW + xb;
#pragma unroll
        for (int oj = 0; oj < 4; ++oj) atomicAdd(op + oj, acc[c][oj]);
    }
}

// ---------------- fallback (ws too small): naive but correct ----------------
__global__ __launch_bounds__(256) void reblur_naive(const float* __restrict__ img,
                                                    const float* __restrict__ Kern,
                                                    float* __restrict__ out) {
    const int lane = threadIdx.x & 63;
    const int dy   = threadIdx.x >> 6;
    const int c    = blockIdx.x >> 8;
    const int bb   = blockIdx.x & 255;
    const int h    = bb >> 1;
    const int wt   = bb & 1;
    const int wb   = wt * 64 + lane;
    const int y    = 4 * h + dy;

    float acc[4] = {0.f, 0.f, 0.f, 0.f};
    const float* kb = Kern + h * NB + wb;
#pragma unroll 1
    for (int u = 0; u < 33; ++u) {
        const int iy = min(max(y + u - 16, 0), HH - 1);
        float row[36];
#pragma unroll
        for (int e = 0; e < 36; ++e) {
            const int ix = min(max(4 * wb + e - 16, 0), WW - 1);
            row[e]       = img[(c * HH + iy) * WW + ix];
        }
#pragma unroll
        for (int v = 0; v < 33; ++v) {
            const float w = kb[(u * 33 + v) * KSTR];
#pragma unroll
            for (int oj = 0; oj < 4; ++oj)
                acc[oj] = fmaf(row[v + oj], w, acc[oj]);
        }
    }
    float4 o;
    o.x = acc[0]; o.y = acc[1]; o.z = acc[2]; o.w = acc[3];
    *reinterpret_cast<float4*>(out + (size_t)(c * HH + y) * WW + 4 * wb) = o;
}

extern "C" void kernel_launch(void* const* d_in, const int* in_sizes, int n_in,
                              void* d_out, int out_size, void* d_ws, size_t ws_size,
                              hipStream_t stream) {
    const float* img  = (const float*)d_in[0];
    const float* Kern = (const float*)d_in[1];
    float* out        = (float*)d_out;

    if (ws_size >= (size_t)PADN * sizeof(unsigned short)) {
        unsigned short* gpad = (unsigned short*)d_ws;
        pad_kernel<<<(PADN + 255) / 256, 256, 0, stream>>>(img, gpad, out);
        reblur_kernel<<<1024, 256, 0, stream>>>(gpad, Kern, out);
    } else {
        reblur_naive<<<768, 256, 0, stream>>>(img, Kern, out);
    }
}

// Round 8
// 292.881 us; speedup vs baseline: 2.2043x; 2.2043x over previous
//
#include <hip/hip_runtime.h>

#define HH 512
#define WW 512
#define PD 544                          // 512 + 2*16
#define PADN (3 * PD * PD)              // 887808 bf16 elements
#define OUTN (3 * HH * WW)
#define NB 128
#define KSTR 16384                      // 128*128 floats between taps

// ---------------- pad + out-zero: fp32 img -> bf16 edge-padded ----------------
__global__ __launch_bounds__(256) void pad_kernel(const float* __restrict__ img,
                                                  unsigned short* __restrict__ gpad,
                                                  float* __restrict__ out) {
    int idx = blockIdx.x * 256 + threadIdx.x;
    if (idx < OUTN) out[idx] = 0.0f;           // zero the atomic target
    if (idx >= PADN) return;
    int c  = idx / (PD * PD);
    int r  = idx - c * (PD * PD);
    int py = r / PD;
    int px = r - py * PD;
    int iy = min(max(py - 16, 0), HH - 1);
    int ix = min(max(px - 16, 0), WW - 1);
    union { float f; unsigned u; } v;
    v.f = img[(c * HH + iy) * WW + ix];
    unsigned u = v.u + 0x7FFFu + ((v.u >> 16) & 1u);   // RNE bf16
    gpad[idx] = (unsigned short)(u >> 16);
}

// ---- async global->LDS (wave-uniform LDS base; HW puts lane i at base+i*size) ----
__device__ __forceinline__ void async16u(const unsigned short* g, unsigned short* l) {
    __builtin_amdgcn_global_load_lds((const __attribute__((address_space(1))) void*)g,
                                     (__attribute__((address_space(3))) void*)l, 16, 0, 0);
}
__device__ __forceinline__ float bflo(unsigned d) { union { unsigned u; float f; } x; x.u = d << 16;         return x.f; }
__device__ __forceinline__ float bfhi(unsigned d) { union { unsigned u; float f; } x; x.u = d & 0xFFFF0000u; return x.f; }

// ---------------- main kernel ----------------
// Grid = 4 u-chunks x 128 h x 2 wt = 1024 blocks of 256 thr (4 waves, wave=dy).
// Lane owns (wb, dy, 3c, 4oj) = 12 accumulators.
// WEIGHTS: global->register direct (L2/L3-resident), double-buffered wA/wB one
// iteration ahead; textual-macro unroll-2 (no dynamic reg indexing, no lambdas,
// no reg-array references -> no scratch; rounds 2/5/7 lessons).
// IMAGE: bf16 rows in an 8-slot LDS ring via global_load_lds; window read =
// 9 ds_read_b64 per channel (8B/lane stride, near-conflict-free).
// Sync per iter: own-stage s_waitcnt vmcnt(0) + one s_barrier.
// OCCUPANCY (round-8 fix): __launch_bounds__(256,2) -- the compiler naturally
// allocates 124 VGPR (measured R6), which PHYSICALLY permits 4 waves/SIMD;
// the (256,4) cap in R7 forced 128-reg spilling (VGPR 64, 1.1 GB scratch).
// 1024 blocks -> 4 blocks/CU = 16 waves/CU. LDS 13.8 KB x4 = 55 KB/CU.
// u-chunks combine via atomicAdd into the pad_kernel-zeroed output.
__global__ __launch_bounds__(256, 2) void reblur_kernel(const unsigned short* __restrict__ gpad,
                                                        const float* __restrict__ Kern,
                                                        float* __restrict__ out) {
    __shared__ unsigned short s_img[8][3][288];   // 13824 B, ring over padded row

    const int lane = threadIdx.x & 63;
    const int dy   = threadIdx.x >> 6;            // wave id 0..3
    const int uq   = blockIdx.x >> 8;             // u-chunk 0..3
    const int bb   = blockIdx.x & 255;
    const int h    = bb >> 1;                     // 0..127
    const int wt   = bb & 1;                      // 0..1
    const int ua   = (uq == 0) ? 0 : (1 + 8 * uq);   // 0,9,17,25
    const int n    = (uq == 0) ? 9 : 8;              // covers u: 0-8,9-16,17-24,25-32
    const int kofs = h * NB + wt * 64 + lane;     // per-lane weight dword offset

    // ---- prologue: wave dy stages image row 4h+ua+dy (x3 channels); all waves
    //      load weight row u=ua into wA ----
    if (lane < 36) {
        const int r = 4 * h + ua + dy;
#pragma unroll
        for (int c = 0; c < 3; ++c)
            async16u(gpad + ((size_t)(c * PD + r) * PD + 256 * wt) + 8 * lane,
                     &s_img[r & 7][c][0]);
    }
    float wA[33], wB[33];
#pragma unroll
    for (int v = 0; v < 33; ++v)
        wA[v] = Kern[(size_t)(ua * 33 + v) * KSTR + kofs];

    float acc[3][4];
#pragma unroll
    for (int c = 0; c < 3; ++c)
#pragma unroll
        for (int oj = 0; oj < 4; ++oj) acc[c][oj] = 0.0f;

// One pipelined iteration. WCUR: weights for u=ua+tt (in regs); WNXT: buffer
// to receive u=ua+tt+1. All array indices compile-time constants.
#define R8_ITER(WCUR, WNXT, TT)                                                  \
    {                                                                            \
        const int tt = (TT);                                                     \
        asm volatile("s_waitcnt vmcnt(0)" ::: "memory");                         \
        __builtin_amdgcn_s_barrier();                                            \
        if (tt + 1 < n) {                                                        \
            const int un = ua + tt + 1;                                          \
            _Pragma("unroll")                                                    \
            for (int v = 0; v < 33; ++v)                                         \
                WNXT[v] = Kern[(size_t)(un * 33 + v) * KSTR + kofs];             \
            if (dy == (tt & 3) && lane < 36) {                                   \
                const int r = 4 * h + ua + tt + 4;                               \
                _Pragma("unroll")                                                \
                for (int c = 0; c < 3; ++c)                                      \
                    async16u(gpad + ((size_t)(c * PD + r) * PD + 256 * wt) + 8 * lane, \
                             &s_img[r & 7][c][0]);                               \
            }                                                                    \
        }                                                                        \
        const int slot = (4 * h + ua + tt + dy) & 7;                             \
        _Pragma("unroll")                                                        \
        for (int c = 0; c < 3; ++c) {                                            \
            float wf[36];                                                        \
            const unsigned short* sp = &s_img[slot][c][4 * lane];                \
            _Pragma("unroll")                                                    \
            for (int j = 0; j < 9; ++j) {                                        \
                const uint2 dd = *(const uint2*)(sp + 4 * j);                    \
                wf[4 * j + 0] = bflo(dd.x);                                      \
                wf[4 * j + 1] = bfhi(dd.x);                                      \
                wf[4 * j + 2] = bflo(dd.y);                                      \
                wf[4 * j + 3] = bfhi(dd.y);                                      \
            }                                                                    \
            _Pragma("unroll")                                                    \
            for (int v = 0; v < 33; ++v) {                                       \
                _Pragma("unroll")                                                \
                for (int oj = 0; oj < 4; ++oj)                                   \
                    acc[c][oj] = fmaf(wf[v + oj], WCUR[v], acc[c][oj]);          \
            }                                                                    \
        }                                                                        \
    }

    int t = 0;
#pragma unroll 1
    for (; t + 1 < n; t += 2) {
        R8_ITER(wA, wB, t);
        R8_ITER(wB, wA, t + 1);
    }
    if (t < n) {           // n odd (chunk 0): tail iter computes with wA
        R8_ITER(wA, wB, t);
    }
#undef R8_ITER

    // ---- epilogue: 4 u-chunks accumulate into the pad_kernel-zeroed output ----
    const int xb = 4 * (wt * 64 + lane);
#pragma unroll
    for (int c = 0; c < 3; ++c) {
        float* op = out + (size_t)(c * HH + 4 * h + dy) * WW + xb;
#pragma unroll
        for (int oj = 0; oj < 4; ++oj) atomicAdd(op + oj, acc[c][oj]);
    }
}

// ---------------- fallback (ws too small): naive but correct ----------------
__global__ __launch_bounds__(256) void reblur_naive(const float* __restrict__ img,
                                                    const float* __restrict__ Kern,
                                                    float* __restrict__ out) {
    const int lane = threadIdx.x & 63;
    const int dy   = threadIdx.x >> 6;
    const int c    = blockIdx.x >> 8;
    const int bb   = blockIdx.x & 255;
    const int h    = bb >> 1;
    const int wt   = bb & 1;
    const int wb   = wt * 64 + lane;
    const int y    = 4 * h + dy;

    float acc[4] = {0.f, 0.f, 0.f, 0.f};
    const float* kb = Kern + h * NB + wb;
#pragma unroll 1
    for (int u = 0; u < 33; ++u) {
        const int iy = min(max(y + u - 16, 0), HH - 1);
        float row[36];
#pragma unroll
        for (int e = 0; e < 36; ++e) {
            const int ix = min(max(4 * wb + e - 16, 0), WW - 1);
            row[e]       = img[(c * HH + iy) * WW + ix];
        }
#pragma unroll
        for (int v = 0; v < 33; ++v) {
            const float w = kb[(u * 33 + v) * KSTR];
#pragma unroll
            for (int oj = 0; oj < 4; ++oj)
                acc[oj] = fmaf(row[v + oj], w, acc[oj]);
        }
    }
    float4 o;
    o.x = acc[0]; o.y = acc[1]; o.z = acc[2]; o.w = acc[3];
    *reinterpret_cast<float4*>(out + (size_t)(c * HH + y) * WW + 4 * wb) = o;
}

extern "C" void kernel_launch(void* const* d_in, const int* in_sizes, int n_in,
                              void* d_out, int out_size, void* d_ws, size_t ws_size,
                              hipStream_t stream) {
    const float* img  = (const float*)d_in[0];
    const float* Kern = (const float*)d_in[1];
    float* out        = (float*)d_out;

    if (ws_size >= (size_t)PADN * sizeof(unsigned short)) {
        unsigned short* gpad = (unsigned short*)d_ws;
        pad_kernel<<<(PADN + 255) / 256, 256, 0, stream>>>(img, gpad, out);
        reblur_kernel<<<1024, 256, 0, stream>>>(gpad, Kern, out);
    } else {
        reblur_naive<<<768, 256, 0, stream>>>(img, Kern, out);
    }
}

// Round 9
// 150.510 us; speedup vs baseline: 4.2893x; 1.9459x over previous
//
#include <hip/hip_runtime.h>

#define HH 512
#define WW 512
#define PD 544                          // 512 + 2*16
#define PADN (3 * PD * PD)              // 887808 bf16 elements
#define OUTN (3 * HH * WW)
#define NB 128
#define KSTR 16384                      // 128*128 floats between taps

// ---------------- pad + out-zero: fp32 img -> bf16 edge-padded ----------------
__global__ __launch_bounds__(256) void pad_kernel(const float* __restrict__ img,
                                                  unsigned short* __restrict__ gpad,
                                                  float* __restrict__ out) {
    int idx = blockIdx.x * 256 + threadIdx.x;
    if (idx < OUTN) out[idx] = 0.0f;           // zero the atomic target
    if (idx >= PADN) return;
    int c  = idx / (PD * PD);
    int r  = idx - c * (PD * PD);
    int py = r / PD;
    int px = r - py * PD;
    int iy = min(max(py - 16, 0), HH - 1);
    int ix = min(max(px - 16, 0), WW - 1);
    union { float f; unsigned u; } v;
    v.f = img[(c * HH + iy) * WW + ix];
    unsigned u = v.u + 0x7FFFu + ((v.u >> 16) & 1u);   // RNE bf16
    gpad[idx] = (unsigned short)(u >> 16);
}

// ---- async global->LDS (wave-uniform LDS base; HW puts lane i at base+i*size) ----
__device__ __forceinline__ void async16u(const unsigned short* g, unsigned short* l) {
    __builtin_amdgcn_global_load_lds((const __attribute__((address_space(1))) void*)g,
                                     (__attribute__((address_space(3))) void*)l, 16, 0, 0);
}
__device__ __forceinline__ float bflo(unsigned d) { union { unsigned u; float f; } x; x.u = d << 16;         return x.f; }
__device__ __forceinline__ float bfhi(unsigned d) { union { unsigned u; float f; } x; x.u = d & 0xFFFF0000u; return x.f; }

// ---------------- main kernel ----------------
// Grid = 4 u-chunks x 128 h x 2 wt = 1024 blocks (4/CU, 16 waves/CU) of 256
// thr (4 waves, wave = dy). Lane owns (wb, dy, 3c, 4oj) = 12 accumulators.
// ROUND-9 CHANGE: no weight double-buffer. wv[33] is loaded at iter top and
// consumed ~300-400cyc later (behind c=0's ds_read+bf16 expand); the residual
// L2-load latency is covered by 4 waves/SIMD TLP. This cuts ~33 live VGPRs:
// R6/R8's wA+wB+wf live set (~130) sat exactly on the 128-reg occupancy
// boundary and spilled on any perturbation (R8: VGPR 128, 413 MB scratch).
// New live set ~95-110 -> 4 waves/SIMD fit physically with NO launch-bounds
// cap ((256,4) forces spill -- R7 lesson; (256,2) kept as non-binding floor).
// IMAGE: bf16 rows in an 8-slot LDS ring via global_load_lds; window read =
// 9 ds_read_b64 per channel (8B/lane stride, near-conflict-free). Sync per
// iter: own-stage s_waitcnt vmcnt(0) + one s_barrier. u-chunks partition u
// and combine via atomicAdd into the pad_kernel-zeroed output.
__global__ __launch_bounds__(256, 2) void reblur_kernel(const unsigned short* __restrict__ gpad,
                                                        const float* __restrict__ Kern,
                                                        float* __restrict__ out) {
    __shared__ unsigned short s_img[8][3][288];   // 13824 B, ring over padded row

    const int lane = threadIdx.x & 63;
    const int dy   = threadIdx.x >> 6;            // wave id 0..3
    const int uq   = blockIdx.x >> 8;             // u-chunk 0..3
    const int bb   = blockIdx.x & 255;
    const int h    = bb >> 1;                     // 0..127
    const int wt   = bb & 1;                      // 0..1
    const int ua   = (uq == 0) ? 0 : (1 + 8 * uq);   // 0,9,17,25
    const int n    = (uq == 0) ? 9 : 8;              // covers u: 0-8,9-16,17-24,25-32
    const int kofs = h * NB + wt * 64 + lane;     // per-lane weight dword offset

    // ---- prologue: wave dy stages image row 4h+ua+dy (x3 channels) ----
    if (lane < 36) {
        const int r = 4 * h + ua + dy;
#pragma unroll
        for (int c = 0; c < 3; ++c)
            async16u(gpad + ((size_t)(c * PD + r) * PD + 256 * wt) + 8 * lane,
                     &s_img[r & 7][c][0]);
    }

    float acc[3][4];
#pragma unroll
    for (int c = 0; c < 3; ++c)
#pragma unroll
        for (int oj = 0; oj < 4; ++oj) acc[c][oj] = 0.0f;

#pragma unroll 1
    for (int tt = 0; tt < n; ++tt) {
        // staged row for THIS iter has landed; everyone done with the slot
        // that the next stage will overwrite
        asm volatile("s_waitcnt vmcnt(0)" ::: "memory");
        __builtin_amdgcn_s_barrier();

        // ---- stage next iter's new image row (rotating wave), fire-and-forget ----
        if (tt + 1 < n && dy == (tt & 3) && lane < 36) {
            const int r = 4 * h + ua + tt + 4;     // max 4*127+25+8+2 = 543
#pragma unroll
            for (int c = 0; c < 3; ++c)
                async16u(gpad + ((size_t)(c * PD + r) * PD + 256 * wt) + 8 * lane,
                         &s_img[r & 7][c][0]);
        }

        // ---- this iter's weight row, global->reg (L2-resident, batched loads;
        //      first use is ~300+cyc later, behind c=0 window read/expand) ----
        float wv[33];
        {
            const int u = ua + tt;
#pragma unroll
            for (int v = 0; v < 33; ++v)
                wv[v] = Kern[(size_t)(u * 33 + v) * KSTR + kofs];
        }

        // ---- window row r = 4h+ua+tt+dy, per channel: read, expand, 132 FMA ----
        const int slot = (4 * h + ua + tt + dy) & 7;
#pragma unroll
        for (int c = 0; c < 3; ++c) {
            float wf[36];
            const unsigned short* sp = &s_img[slot][c][4 * lane];
#pragma unroll
            for (int j = 0; j < 9; ++j) {
                const uint2 dd = *(const uint2*)(sp + 4 * j);
                wf[4 * j + 0] = bflo(dd.x);
                wf[4 * j + 1] = bfhi(dd.x);
                wf[4 * j + 2] = bflo(dd.y);
                wf[4 * j + 3] = bfhi(dd.y);
            }
#pragma unroll
            for (int v = 0; v < 33; ++v) {
#pragma unroll
                for (int oj = 0; oj < 4; ++oj)
                    acc[c][oj] = fmaf(wf[v + oj], wv[v], acc[c][oj]);
            }
        }
    }

    // ---- epilogue: 4 u-chunks accumulate into the pad_kernel-zeroed output ----
    const int xb = 4 * (wt * 64 + lane);
#pragma unroll
    for (int c = 0; c < 3; ++c) {
        float* op = out + (size_t)(c * HH + 4 * h + dy) * WW + xb;
#pragma unroll
        for (int oj = 0; oj < 4; ++oj) atomicAdd(op + oj, acc[c][oj]);
    }
}

// ---------------- fallback (ws too small): naive but correct ----------------
__global__ __launch_bounds__(256) void reblur_naive(const float* __restrict__ img,
                                                    const float* __restrict__ Kern,
                                                    float* __restrict__ out) {
    const int lane = threadIdx.x & 63;
    const int dy   = threadIdx.x >> 6;
    const int c    = blockIdx.x >> 8;
    const int bb   = blockIdx.x & 255;
    const int h    = bb >> 1;
    const int wt   = bb & 1;
    const int wb   = wt * 64 + lane;
    const int y    = 4 * h + dy;

    float acc[4] = {0.f, 0.f, 0.f, 0.f};
    const float* kb = Kern + h * NB + wb;
#pragma unroll 1
    for (int u = 0; u < 33; ++u) {
        const int iy = min(max(y + u - 16, 0), HH - 1);
        float row[36];
#pragma unroll
        for (int e = 0; e < 36; ++e) {
            const int ix = min(max(4 * wb + e - 16, 0), WW - 1);
            row[e]       = img[(c * HH + iy) * WW + ix];
        }
#pragma unroll
        for (int v = 0; v < 33; ++v) {
            const float w = kb[(u * 33 + v) * KSTR];
#pragma unroll
            for (int oj = 0; oj < 4; ++oj)
                acc[oj] = fmaf(row[v + oj], w, acc[oj]);
        }
    }
    float4 o;
    o.x = acc[0]; o.y = acc[1]; o.z = acc[2]; o.w = acc[3];
    *reinterpret_cast<float4*>(out + (size_t)(c * HH + y) * WW + 4 * wb) = o;
}

extern "C" void kernel_launch(void* const* d_in, const int* in_sizes, int n_in,
                              void* d_out, int out_size, void* d_ws, size_t ws_size,
                              hipStream_t stream) {
    const float* img  = (const float*)d_in[0];
    const float* Kern = (const float*)d_in[1];
    float* out        = (float*)d_out;

    if (ws_size >= (size_t)PADN * sizeof(unsigned short)) {
        unsigned short* gpad = (unsigned short*)d_ws;
        pad_kernel<<<(PADN + 255) / 256, 256, 0, stream>>>(img, gpad, out);
        reblur_kernel<<<1024, 256, 0, stream>>>(gpad, Kern, out);
    } else {
        reblur_naive<<<768, 256, 0, stream>>>(img, Kern, out);
    }
}